// Round 13
// baseline (139.605 us; speedup 1.0000x reference)
//
#include <hip/hip_runtime.h>

#define U_CNT 16384
#define I_CNT 8192
#define DIM 64
#define BAND 16                   // rows per band (per block per step)
#define CHUNK 256                 // cols owned by one block (fixed)
#define NSTEP 32                  // bands per group sweep
#define LDS_STRIDE 68             // floats; 68 % 32 == 4 -> 2-way conflicts only (free)
#define NEG_LOG2E (-1.4426950408889634f)

typedef __bf16 bf16x8 __attribute__((ext_vector_type(8)));
typedef float f32x4 __attribute__((ext_vector_type(4)));
typedef unsigned short ushort4v __attribute__((ext_vector_type(4)));

__device__ __forceinline__ unsigned short f32_to_bf16_rtn(float f) {
    unsigned int b = __float_as_uint(f);
    b += 0x7fffu + ((b >> 16) & 1u);
    return (unsigned short)(b >> 16);
}

// Prep: blocks [0, 2048) convert Q1 -> bf16; blocks [2048, ...) scan seg_ids
// for segment boundaries (every user has >=1 item -> every bounds[u] written
// exactly once; bounds[U_CNT] = nnz). UNCHANGED from champion.
__global__ __launch_bounds__(256) void prep_kernel(
    const float* __restrict__ Q1, unsigned short* __restrict__ Q1bf,
    const int* __restrict__ segs, int nnz, int* __restrict__ bounds)
{
    if (blockIdx.x < 2048) {
        int i = blockIdx.x * 256 + threadIdx.x;   // covers I_CNT*DIM = 524288
        Q1bf[i] = f32_to_bf16_rtn(Q1[i]);
    } else {
        int i = (blockIdx.x - 2048) * 256 + threadIdx.x;
        if (i >= nnz) return;
        if (i == 0) bounds[segs[0]] = 0;
        else if (segs[i] != segs[i - 1]) bounds[segs[i]] = i;
        if (i == nnz - 1) bounds[U_CNT] = nnz;
    }
}

// One wave per user, quarter-wave per item (the R12 vectorized gather):
// lane l loads a 16B f32x4 of row items[j + (l>>4)], dims 4*(l&15)..+3;
// dual accumulators; 8-shuffle cross-quarter reduce; lanes 0-15 finalize
// with an 8B ushort4 bf16 store. UNCHANGED from champion.
__global__ __launch_bounds__(256) void pfull_kernel(
    const float* __restrict__ Q2, const float* __restrict__ P,
    const int* __restrict__ items, const int* __restrict__ bounds,
    unsigned short* __restrict__ Pbf)
{
    const int u = (blockIdx.x * 256 + threadIdx.x) >> 6;
    const int lane = threadIdx.x & 63;
    if (u >= U_CNT) return;
    const int qg = lane >> 4;       // quarter-group: which item in a 4-pack
    const int ql = lane & 15;       // dim slot: 16 lanes x f32x4 = 64 dims

    const int start = bounds[u];
    const int end   = bounds[u + 1];
    const int cnt   = end - start;  // guaranteed >= 1

    f32x4 acc0 = {0.f, 0.f, 0.f, 0.f}, acc1 = {0.f, 0.f, 0.f, 0.f};
    int j = start + qg;
    for (; j + 4 < end; j += 8) {
        int i0 = items[j], i1 = items[j + 4];
        f32x4 v0 = *reinterpret_cast<const f32x4*>(&Q2[i0 * DIM + ql * 4]);
        f32x4 v1 = *reinterpret_cast<const f32x4*>(&Q2[i1 * DIM + ql * 4]);
        acc0 += v0;
        acc1 += v1;
    }
    if (j < end)
        acc0 += *reinterpret_cast<const f32x4*>(&Q2[items[j] * DIM + ql * 4]);
    f32x4 acc = acc0 + acc1;

    // Reduce across the 4 quarter-groups (lanes l, l+16, l+32, l+48).
#pragma unroll
    for (int e = 0; e < 4; ++e) {
        acc[e] += __shfl_xor(acc[e], 16, 64);
        acc[e] += __shfl_xor(acc[e], 32, 64);
    }

    if (qg == 0) {
        f32x4 pv = *reinterpret_cast<const f32x4*>(&P[u * DIM + ql * 4]);
        float rs = rsqrtf((float)cnt);
        ushort4v o;
#pragma unroll
        for (int e = 0; e < 4; ++e)
            o[e] = f32_to_bf16_rtn(acc[e] * rs + pv[e]);
        *reinterpret_cast<ushort4v*>(&Pbf[u * DIM + ql * 4]) = o;
    }
}

// Coordinated-window GEMM + sigmoid. SINGLE CHANGE vs the 121.9us champion:
// output stores are PLAIN (cached) instead of nontemporal. Theory: nt's +11us
// win (R7) was measured in the scattered-stream regime where it avoided L3
// eviction scramble; in the coordinated-window regime the live write set is
// a linear 16MB window, so cached stores should write-combine our 256B
// per-instruction row-segments into full lines in L2/L3 and evict
// quasi-linearly — fixing the granule fragmentation that nt forwards
// straight to HBM. Everything else byte-identical.
__global__ __launch_bounds__(256) void gemm_sig_kernel(
    const unsigned short* __restrict__ Abf, const unsigned short* __restrict__ Bbf,
    const float* __restrict__ bu, const float* __restrict__ bi,
    float* __restrict__ out)
{
    const int lane = threadIdx.x & 63;
    const int wid  = threadIdx.x >> 6;      // 0..3: 64-col sub-band within chunk
    const int r = lane & 15, g = lane >> 4;
    const int member = blockIdx.x & 31;     // fixed col chunk
    const int group  = blockIdx.x >> 5;     // 0..31
    const int col0 = member * CHUNK + wid * 64;

    __shared__ float lds_all[4][BAND * LDS_STRIDE];
    float* lds = lds_all[wid];              // per-wave private region

    // B fragments + bi: loaded ONCE, register-resident for the whole kernel.
    bf16x8 b[4][2];
    float bi_f[4];
#pragma unroll
    for (int nf = 0; nf < 4; ++nf) {
        bi_f[nf] = bi[col0 + nf * 16 + r] + 0.05f;   // fold the +0.05 here
#pragma unroll
        for (int ks = 0; ks < 2; ++ks)
            b[nf][ks] = *reinterpret_cast<const bf16x8*>(
                &Bbf[(col0 + nf * 16 + r) * DIM + ks * 32 + g * 8]);
    }

    for (int s = 0; s < NSTEP; ++s) {
        const int band = (group + s * 32) * BAND;

        // A fragment for this band (rows band..band+15), both K-steps.
        bf16x8 a[2];
#pragma unroll
        for (int ks = 0; ks < 2; ++ks)
            a[ks] = *reinterpret_cast<const bf16x8*>(
                &Abf[(band + r) * DIM + ks * 32 + g * 8]);

        float bu_g[4];
#pragma unroll
        for (int j = 0; j < 4; ++j) bu_g[j] = bu[band + g * 4 + j];

        f32x4 acc[4] = {};
#pragma unroll
        for (int ks = 0; ks < 2; ++ks)
#pragma unroll
            for (int nf = 0; nf < 4; ++nf)
                acc[nf] = __builtin_amdgcn_mfma_f32_16x16x32_bf16(
                    a[ks], b[nf][ks], acc[nf], 0, 0, 0);

        // Sigmoid in acc layout (row = g*4+j, col = nf*16+r), then transpose
        // through per-wave LDS.
#pragma unroll
        for (int nf = 0; nf < 4; ++nf)
#pragma unroll
            for (int j = 0; j < 4; ++j) {
                float x = (acc[nf][j] + bu_g[j] + bi_f[nf]) * NEG_LOG2E;
                float e = __builtin_amdgcn_exp2f(x);
                float v = 5.f * __builtin_amdgcn_rcpf(1.f + e);
                lds[(g * 4 + j) * LDS_STRIDE + nf * 16 + r] = v;
            }

        // Store: instr i covers rows i*4..i*4+3 (g picks row, r picks 16B
        // slot): 256B contiguous per row, full cache lines, PLAIN stores.
#pragma unroll
        for (int i = 0; i < 4; ++i) {
            const int row = i * 4 + g;
            f32x4 v = *reinterpret_cast<const f32x4*>(&lds[row * LDS_STRIDE + r * 4]);
            *reinterpret_cast<f32x4*>(
                &out[(size_t)(band + row) * I_CNT + col0 + r * 4]) = v;
        }
    }
}

extern "C" void kernel_launch(void* const* d_in, const int* in_sizes, int n_in,
                              void* d_out, int out_size, void* d_ws, size_t ws_size,
                              hipStream_t stream)
{
    const float* Q1 = (const float*)d_in[0];
    const float* Q2 = (const float*)d_in[1];
    const float* P  = (const float*)d_in[2];
    const float* bu = (const float*)d_in[3];
    const float* bi = (const float*)d_in[4];
    const int* items = (const int*)d_in[5];
    const int* segs  = (const int*)d_in[6];
    const int nnz = in_sizes[5];

    unsigned short* Pbf  = (unsigned short*)d_ws;            // 2 MB
    unsigned short* Q1bf = Pbf + U_CNT * DIM;                // 1 MB
    int* bounds = (int*)(Q1bf + I_CNT * DIM);                // 64 KB + 4 B

    int boundsBlocks = (nnz + 255) / 256;
    prep_kernel<<<2048 + boundsBlocks, 256, 0, stream>>>(Q1, Q1bf, segs, nnz, bounds);
    pfull_kernel<<<U_CNT / 4, 256, 0, stream>>>(Q2, P, items, bounds, Pbf);
    // 32 groups x 32 members = 1024 blocks; each block sweeps NSTEP=32 bands.
    gemm_sig_kernel<<<32 * 32, 256, 0, stream>>>(Pbf, Q1bf, bu, bi, (float*)d_out);
}

// Round 14
// 114.794 us; speedup vs baseline: 1.2161x; 1.2161x over previous
//
#include <hip/hip_runtime.h>

#define U_CNT 16384
#define I_CNT 8192
#define DIM 64
#define BAND 16                   // rows per band (per block per step)
#define CHUNK 256                 // cols owned by one block (fixed)
#define NSTEP 32                  // bands per group sweep
#define LDS_STRIDE 260            // floats; 260%32=4 -> write 2-way (free), read clean
#define NEG_LOG2E (-1.4426950408889634f)

typedef __bf16 bf16x8 __attribute__((ext_vector_type(8)));
typedef float f32x4 __attribute__((ext_vector_type(4)));
typedef unsigned short ushort4v __attribute__((ext_vector_type(4)));

__device__ __forceinline__ unsigned short f32_to_bf16_rtn(float f) {
    unsigned int b = __float_as_uint(f);
    b += 0x7fffu + ((b >> 16) & 1u);
    return (unsigned short)(b >> 16);
}

// Prep: blocks [0, 2048) convert Q1 -> bf16; blocks [2048, ...) scan seg_ids
// for segment boundaries. UNCHANGED from champion.
__global__ __launch_bounds__(256) void prep_kernel(
    const float* __restrict__ Q1, unsigned short* __restrict__ Q1bf,
    const int* __restrict__ segs, int nnz, int* __restrict__ bounds)
{
    if (blockIdx.x < 2048) {
        int i = blockIdx.x * 256 + threadIdx.x;   // covers I_CNT*DIM = 524288
        Q1bf[i] = f32_to_bf16_rtn(Q1[i]);
    } else {
        int i = (blockIdx.x - 2048) * 256 + threadIdx.x;
        if (i >= nnz) return;
        if (i == 0) bounds[segs[0]] = 0;
        else if (segs[i] != segs[i - 1]) bounds[segs[i]] = i;
        if (i == nnz - 1) bounds[U_CNT] = nnz;
    }
}

// One wave per user, quarter-wave per item (R12 vectorized gather).
// UNCHANGED from champion.
__global__ __launch_bounds__(256) void pfull_kernel(
    const float* __restrict__ Q2, const float* __restrict__ P,
    const int* __restrict__ items, const int* __restrict__ bounds,
    unsigned short* __restrict__ Pbf)
{
    const int u = (blockIdx.x * 256 + threadIdx.x) >> 6;
    const int lane = threadIdx.x & 63;
    if (u >= U_CNT) return;
    const int qg = lane >> 4;       // quarter-group: which item in a 4-pack
    const int ql = lane & 15;       // dim slot: 16 lanes x f32x4 = 64 dims

    const int start = bounds[u];
    const int end   = bounds[u + 1];
    const int cnt   = end - start;  // guaranteed >= 1

    f32x4 acc0 = {0.f, 0.f, 0.f, 0.f}, acc1 = {0.f, 0.f, 0.f, 0.f};
    int j = start + qg;
    for (; j + 4 < end; j += 8) {
        int i0 = items[j], i1 = items[j + 4];
        f32x4 v0 = *reinterpret_cast<const f32x4*>(&Q2[i0 * DIM + ql * 4]);
        f32x4 v1 = *reinterpret_cast<const f32x4*>(&Q2[i1 * DIM + ql * 4]);
        acc0 += v0;
        acc1 += v1;
    }
    if (j < end)
        acc0 += *reinterpret_cast<const f32x4*>(&Q2[items[j] * DIM + ql * 4]);
    f32x4 acc = acc0 + acc1;

    // Reduce across the 4 quarter-groups (lanes l, l+16, l+32, l+48).
#pragma unroll
    for (int e = 0; e < 4; ++e) {
        acc[e] += __shfl_xor(acc[e], 16, 64);
        acc[e] += __shfl_xor(acc[e], 32, 64);
    }

    if (qg == 0) {
        f32x4 pv = *reinterpret_cast<const f32x4*>(&P[u * DIM + ql * 4]);
        float rs = rsqrtf((float)cnt);
        ushort4v o;
#pragma unroll
        for (int e = 0; e < 4; ++e)
            o[e] = f32_to_bf16_rtn(acc[e] * rs + pv[e]);
        *reinterpret_cast<ushort4v*>(&Pbf[u * DIM + ql * 4]) = o;
    }
}

// Coordinated-window GEMM + sigmoid. SINGLE CHANGE vs the 121.9us champion:
// the epilogue transpose goes through a BLOCK-wide LDS tile [16][260]
// (16.6 KB — preserves 4 blocks/CU residency, required for the window),
// and each nt store instruction now writes 1 KB FULLY CONTIGUOUS of one
// output row (64 lanes x 16B) instead of 4x 256B row-segments. nt forwards
// granules straight to HBM (no downstream merge — R13 proved the cached
// path loses 18us), so per-instruction granule is the last untested store
// variable. Two barriers per step. Banks: write 2-way (free), read clean.
__global__ __launch_bounds__(256) void gemm_sig_kernel(
    const unsigned short* __restrict__ Abf, const unsigned short* __restrict__ Bbf,
    const float* __restrict__ bu, const float* __restrict__ bi,
    float* __restrict__ out)
{
    const int lane = threadIdx.x & 63;
    const int wid  = threadIdx.x >> 6;      // 0..3: 64-col sub-band within chunk
    const int r = lane & 15, g = lane >> 4;
    const int member = blockIdx.x & 31;     // fixed col chunk
    const int group  = blockIdx.x >> 5;     // 0..31
    const int colbase = member * CHUNK;
    const int col0 = colbase + wid * 64;

    __shared__ float lds[BAND][LDS_STRIDE];   // block-wide, single-buffered

    // B fragments + bi: loaded ONCE, register-resident for the whole kernel.
    bf16x8 b[4][2];
    float bi_f[4];
#pragma unroll
    for (int nf = 0; nf < 4; ++nf) {
        bi_f[nf] = bi[col0 + nf * 16 + r] + 0.05f;   // fold the +0.05 here
#pragma unroll
        for (int ks = 0; ks < 2; ++ks)
            b[nf][ks] = *reinterpret_cast<const bf16x8*>(
                &Bbf[(col0 + nf * 16 + r) * DIM + ks * 32 + g * 8]);
    }

    for (int s = 0; s < NSTEP; ++s) {
        const int band = (group + s * 32) * BAND;

        // A fragment for this band (rows band..band+15), both K-steps.
        bf16x8 a[2];
#pragma unroll
        for (int ks = 0; ks < 2; ++ks)
            a[ks] = *reinterpret_cast<const bf16x8*>(
                &Abf[(band + r) * DIM + ks * 32 + g * 8]);

        float bu_g[4];
#pragma unroll
        for (int j = 0; j < 4; ++j) bu_g[j] = bu[band + g * 4 + j];

        f32x4 acc[4] = {};
#pragma unroll
        for (int ks = 0; ks < 2; ++ks)
#pragma unroll
            for (int nf = 0; nf < 4; ++nf)
                acc[nf] = __builtin_amdgcn_mfma_f32_16x16x32_bf16(
                    a[ks], b[nf][ks], acc[nf], 0, 0, 0);

        // Sigmoid in acc layout (row = g*4+j, col = wid*64 + nf*16 + r),
        // write into the block-wide tile.
#pragma unroll
        for (int nf = 0; nf < 4; ++nf)
#pragma unroll
            for (int j = 0; j < 4; ++j) {
                float x = (acc[nf][j] + bu_g[j] + bi_f[nf]) * NEG_LOG2E;
                float e = __builtin_amdgcn_exp2f(x);
                float v = 5.f * __builtin_amdgcn_rcpf(1.f + e);
                lds[g * 4 + j][wid * 64 + nf * 16 + r] = v;
            }

        __syncthreads();

        // Store phase: wave wid owns rows wid*4..wid*4+3. ONE instruction
        // per row: 64 lanes x f32x4 = 1 KB fully contiguous, nontemporal.
#pragma unroll
        for (int i = 0; i < 4; ++i) {
            const int row = wid * 4 + i;
            f32x4 v = *reinterpret_cast<const f32x4*>(&lds[row][lane * 4]);
            __builtin_nontemporal_store(v, reinterpret_cast<f32x4*>(
                &out[(size_t)(band + row) * I_CNT + colbase + lane * 4]));
        }

        __syncthreads();   // protect tile reuse by next step
    }
}

extern "C" void kernel_launch(void* const* d_in, const int* in_sizes, int n_in,
                              void* d_out, int out_size, void* d_ws, size_t ws_size,
                              hipStream_t stream)
{
    const float* Q1 = (const float*)d_in[0];
    const float* Q2 = (const float*)d_in[1];
    const float* P  = (const float*)d_in[2];
    const float* bu = (const float*)d_in[3];
    const float* bi = (const float*)d_in[4];
    const int* items = (const int*)d_in[5];
    const int* segs  = (const int*)d_in[6];
    const int nnz = in_sizes[5];

    unsigned short* Pbf  = (unsigned short*)d_ws;            // 2 MB
    unsigned short* Q1bf = Pbf + U_CNT * DIM;                // 1 MB
    int* bounds = (int*)(Q1bf + I_CNT * DIM);                // 64 KB + 4 B

    int boundsBlocks = (nnz + 255) / 256;
    prep_kernel<<<2048 + boundsBlocks, 256, 0, stream>>>(Q1, Q1bf, segs, nnz, bounds);
    pfull_kernel<<<U_CNT / 4, 256, 0, stream>>>(Q2, P, items, bounds, Pbf);
    // 32 groups x 32 members = 1024 blocks; each block sweeps NSTEP=32 bands.
    gemm_sig_kernel<<<32 * 32, 256, 0, stream>>>(Pbf, Q1bf, bu, bi, (float*)d_out);
}